// Round 1
// baseline (55.630 us; speedup 1.0000x reference)
//
#include <hip/hip_runtime.h>

// Analytic collapse of the reference "quantum circuit":
// per 8-element group, with c_j = cos(x_j + theta_j):
//   out_0 = c1*c2*c3*c4*c5*c6*c7
//   out_i = c0*...*ci   (i = 1..7)
// Derivation: RX product state => independent qubits, P(a_j=1)=sin^2(phi_j/2);
// CNOT chain is a basis permutation with f_i = XOR(a_0..a_i) (i>=1),
// f_0 = XOR(a_1..a_7); <Z_i> = prod over the XOR set of (1-2p_j) = prod cos(phi_j).

__global__ __launch_bounds__(256) void qc_prefix_cos_kernel(
    const float* __restrict__ x,
    const float* __restrict__ theta,
    float* __restrict__ out,
    int n_groups)
{
    int g = blockIdx.x * blockDim.x + threadIdx.x;
    if (g >= n_groups) return;

    // theta: 8 floats, broadcast (L1-resident)
    const float4* tv = (const float4*)theta;
    float4 t0 = tv[0];
    float4 t1 = tv[1];

    const float4* xv = (const float4*)x + (size_t)g * 2;
    float4 a = xv[0];
    float4 b = xv[1];

    float c0 = __cosf(a.x + t0.x);
    float c1 = __cosf(a.y + t0.y);
    float c2 = __cosf(a.z + t0.z);
    float c3 = __cosf(a.w + t0.w);
    float c4 = __cosf(b.x + t1.x);
    float c5 = __cosf(b.y + t1.y);
    float c6 = __cosf(b.z + t1.z);
    float c7 = __cosf(b.w + t1.w);

    // prefix products p_i = c0*...*ci
    float p1 = c0 * c1;
    float p2 = p1 * c2;
    float p3 = p2 * c3;
    float p4 = p3 * c4;
    float p5 = p4 * c5;
    float p6 = p5 * c6;
    float p7 = p6 * c7;

    // suffix product for out_0 = c1*...*c7 (avoid dividing p7 by c0)
    float s = c1 * c2;
    s *= c3;
    s *= c4;
    s *= c5;
    s *= c6;
    s *= c7;

    float4 o0 = make_float4(s,  p1, p2, p3);
    float4 o1 = make_float4(p4, p5, p6, p7);

    float4* ov = (float4*)out + (size_t)g * 2;
    ov[0] = o0;
    ov[1] = o1;
}

extern "C" void kernel_launch(void* const* d_in, const int* in_sizes, int n_in,
                              void* d_out, int out_size, void* d_ws, size_t ws_size,
                              hipStream_t stream) {
    const float* x     = (const float*)d_in[0];
    const float* theta = (const float*)d_in[1];
    float* out = (float*)d_out;

    int n_groups = out_size / 8;  // 65536 for (2,512,512)
    const int block = 256;
    int grid = (n_groups + block - 1) / block;
    qc_prefix_cos_kernel<<<grid, block, 0, stream>>>(x, theta, out, n_groups);
}